// Round 4
// baseline (87.558 us; speedup 1.0000x reference)
//
#include <hip/hip_runtime.h>
#include <cstdint>
#include <cstddef>

#define S      4096
#define BATCH  16
#define BLK    256
#define YSPAN  2048                 // y range per block (z-dim splits S into 2)
#define CHUNK  512                  // y points staged per chunk
#define NTILE  (CHUNK / 32)         // 16 tiles of 32 y-points
#define NCHUNK (YSPAN / CHUNK)      // 4
#define ROWS_PER_BLOCK 128          // 4 waves x 32 rows
#define XC_N   (S / ROWS_PER_BLOCK) // 32 x-chunks
#define YC_N   (S / YSPAN)          // 2 y-slabs

typedef _Float16 half8   __attribute__((ext_vector_type(8)));
typedef float    floatx16 __attribute__((ext_vector_type(16)));

__device__ inline unsigned pack2(_Float16 lo, _Float16 hi) {
    unsigned short a = __builtin_bit_cast(unsigned short, lo);
    unsigned short b = __builtin_bit_cast(unsigned short, hi);
    return (unsigned)a | ((unsigned)b << 16);
}

// ---------------------------------------------------------------------------
// One MFMA per 32x32 tile computes D = d^2/2 for 1024 pairs:
//   A lanes 0-31  (k0-7):  [-xh0,-xh1,-xh2, -xh0,-xh1,-xh2, -xl0,-xl1]
//   A lanes 32-63 (k8-15): [-xl2, 1, 1, xnh, xnl, 0, 0, 0]
//   B lanes 0-31  (k0-7):  [yh0,yh1,yh2, yl0,yl1,yl2, yh0,yh1]
//   B lanes 32-63 (k8-15): [yh2, hh, hl, 1, 1, 0, 0, 0]
// where *h/*l = f16 hi/lo split, h = |y|^2/2, xn = |x|^2/2.
// D = xn + h - x.y = d^2/2 (error ~1e-6).  C/D: col=lane&31,
// row=(reg&3)+8*(reg>>2)+4*(lane>>5).
//
// No global atomics: block (xc,b,yc) writes its final row-mins (over its
// y-slab) to ws0[yc][b][128 rows], and its col-min partials (over its 128
// rows) to ws1[xc][b][2048 cols]. Every slot written exactly once -> no
// workspace init needed (kills the 39us rocclr fill that dominated R3).
// ---------------------------------------------------------------------------
__global__ __launch_bounds__(BLK) void chamfer_mfma_kernel(
    const float* __restrict__ x, const float* __restrict__ y,
    float* __restrict__ ws0, float* __restrict__ ws1)
{
    const int b    = blockIdx.y;
    const int xc   = blockIdx.x;          // 0..31
    const int yc   = blockIdx.z;          // 0..1
    const int tid  = threadIdx.x;
    const int lane = tid & 63;
    const int wave = tid >> 6;            // 0..3
    const int hi32 = lane >> 5;
    const int l31  = lane & 31;

    __shared__ uint4    ldsb[2][NTILE][64];
    __shared__ unsigned colmin[YSPAN];

    for (int i = tid; i < YSPAN; i += BLK) colmin[i] = 0x7F7F7F7Fu;
    // constant .z/.w of the upper-lane B slots: [e4=1, e5..7=0]
    for (int i = tid; i < 2 * NTILE * 32; i += BLK) {
        int bu = i / (NTILE * 32); int r = i % (NTILE * 32);
        ldsb[bu][r >> 5][32 + (r & 31)].z = 0x00003C00u;  // pack(1.0h, 0h)
        ldsb[bu][r >> 5][32 + (r & 31)].w = 0u;
    }

    // ---- A fragment (this wave's 32 x-rows; both lane-halves load same row)
    const int row = xc * ROWS_PER_BLOCK + wave * 32 + l31;
    const float* xp = x + ((size_t)b * S + row) * 3;
    const float x0 = xp[0], x1 = xp[1], x2 = xp[2];
    const float xn = 0.5f * (x0 * x0 + x1 * x1 + x2 * x2);
    const _Float16 xh0 = (_Float16)x0, xh1 = (_Float16)x1, xh2 = (_Float16)x2;
    const _Float16 xl0 = (_Float16)(x0 - (float)xh0);
    const _Float16 xl1 = (_Float16)(x1 - (float)xh1);
    const _Float16 xl2 = (_Float16)(x2 - (float)xh2);
    const _Float16 xnh = (_Float16)xn;
    const _Float16 xnl = (_Float16)(xn - (float)xnh);
    half8 afrag;
    if (hi32 == 0) {
        afrag[0] = -xh0; afrag[1] = -xh1; afrag[2] = -xh2;
        afrag[3] = -xh0; afrag[4] = -xh1; afrag[5] = -xh2;
        afrag[6] = -xl0; afrag[7] = -xl1;
    } else {
        afrag[0] = -xl2; afrag[1] = (_Float16)1.0f; afrag[2] = (_Float16)1.0f;
        afrag[3] = xnh;  afrag[4] = xnl;
        afrag[5] = (_Float16)0.0f; afrag[6] = (_Float16)0.0f; afrag[7] = (_Float16)0.0f;
    }

    floatx16 runrow;
#pragma unroll
    for (int r = 0; r < 16; ++r) runrow[r] = 3.0e38f;
    const floatx16 zeroacc = {};

    const int ybase = yc * YSPAN;
    const float* ysrc = y + ((size_t)b * S + ybase) * 3;

    auto stage = [&](int cc) {
        const int buf = cc & 1;
#pragma unroll
        for (int q = 0; q < 2; ++q) {
            const int pl = tid * 2 + q;            // 0..CHUNK
            const int p  = cc * CHUNK + pl;        // within YSPAN
            const float* yp = ysrc + (size_t)p * 3;
            const float y0 = yp[0], y1 = yp[1], y2 = yp[2];
            const float h  = 0.5f * (y0 * y0 + y1 * y1 + y2 * y2);
            const _Float16 a0 = (_Float16)y0, a1 = (_Float16)y1, a2 = (_Float16)y2;
            const _Float16 b0 = (_Float16)(y0 - (float)a0);
            const _Float16 b1 = (_Float16)(y1 - (float)a1);
            const _Float16 b2 = (_Float16)(y2 - (float)a2);
            const _Float16 hh = (_Float16)h;
            const _Float16 hl = (_Float16)(h - (float)hh);
            const int t = pl >> 5, col = pl & 31;
            ldsb[buf][t][col] = make_uint4(pack2(a0, a1), pack2(a2, b0),
                                           pack2(b1, b2), pack2(a0, a1));
            *(uint2*)&ldsb[buf][t][32 + col] =
                make_uint2(pack2(a2, hh), pack2(hl, (_Float16)1.0f));
        }
    };

    stage(0);
    __syncthreads();

    for (int c = 0; c < NCHUNK; ++c) {
        if (c + 1 < NCHUNK) stage(c + 1);
        const int buf = c & 1;
#pragma unroll 4
        for (int t = 0; t < NTILE; ++t) {
            const uint4 braw = ldsb[buf][t][lane];
            const half8 bfrag = __builtin_bit_cast(half8, braw);
            const floatx16 d =
                __builtin_amdgcn_mfma_f32_32x32x16_f16(afrag, bfrag, zeroacc, 0, 0, 0);
            // x-direction: running row mins (16 rows per lane)
#pragma unroll
            for (int r = 0; r < 16; ++r) runrow[r] = fminf(runrow[r], d[r]);
            // y-direction: fold 16 regs (min3-fusable chains), then lane-halves
            float m = fminf(fminf(d[0], d[1]), d[2]);
            m = fminf(fminf(m, d[3]), d[4]);
            m = fminf(fminf(m, d[5]), d[6]);
            m = fminf(fminf(m, d[7]), d[8]);
            m = fminf(fminf(m, d[9]), d[10]);
            m = fminf(fminf(m, d[11]), d[12]);
            m = fminf(fminf(m, d[13]), d[14]);
            m = fminf(m, d[15]);
            m = fminf(m, __shfl_xor(m, 32));
            m = fmaxf(m, 0.0f);
            if (lane < 32)
                atomicMin(&colmin[c * CHUNK + t * 32 + l31], __float_as_uint(m));
        }
        __syncthreads();
    }

    // ---- x-direction flush: butterfly over the 32 cols, plain store rows
#pragma unroll
    for (int r = 0; r < 16; ++r) {
        float v = runrow[r];
        v = fminf(v, __shfl_xor(v, 1));
        v = fminf(v, __shfl_xor(v, 2));
        v = fminf(v, __shfl_xor(v, 4));
        v = fminf(v, __shfl_xor(v, 8));
        v = fminf(v, __shfl_xor(v, 16));
        runrow[r] = v;
    }
    if (l31 == 0) {
        float* w0 = ws0 + ((size_t)yc * BATCH + b) * S
                        + xc * ROWS_PER_BLOCK + wave * 32;
#pragma unroll
        for (int r = 0; r < 16; ++r) {
            const int rr = (r & 3) + 8 * (r >> 2) + 4 * hi32;
            w0[rr] = fmaxf(runrow[r], 0.0f);
        }
    }

    // ---- y-direction flush (loop-end barrier already synced all LDS mins)
    float* w1 = ws1 + ((size_t)xc * BATCH + b) * S + ybase;
    for (int i = tid; i < YSPAN; i += BLK)
        w1[i] = __uint_as_float(colmin[i]);
}

// ---------------------------------------------------------------------------
// Pass 2: fold ws0 over 2 y-slabs and ws1 over 32 x-chunks, then
// mean of sqrt(2 * d^2/2). One block per batch, direct store to out[b].
// ---------------------------------------------------------------------------
#define RBLK 512
__global__ __launch_bounds__(RBLK) void chamfer_reduce_kernel(
    const float* __restrict__ ws0, const float* __restrict__ ws1,
    float* __restrict__ out)
{
    const int b = blockIdx.x;
    const int tid = threadIdx.x;
    float s = 0.0f;

    // x-direction rows: min over the 2 y-slabs
    for (int i = tid; i < S; i += RBLK) {
        const float m = fminf(ws0[(size_t)b * S + i],
                              ws0[((size_t)BATCH + b) * S + i]);
        s += sqrtf(2.0f * m);
    }
    // y-direction cols: min over the 32 x-chunk partials
    for (int i = tid; i < S; i += RBLK) {
        float m = 3.0e38f;
#pragma unroll 8
        for (int xc = 0; xc < XC_N; ++xc)
            m = fminf(m, ws1[((size_t)xc * BATCH + b) * S + i]);
        s += sqrtf(2.0f * m);
    }

    __shared__ float red[RBLK];
    red[tid] = s;
    __syncthreads();
    for (int off = RBLK / 2; off > 0; off >>= 1) {
        if (tid < off) red[tid] += red[tid + off];
        __syncthreads();
    }
    if (tid == 0) out[b] = red[0] * (0.5f / (float)S);
}

// ---------------------------------------------------------------------------
// Fallback (no workspace): scalar full-range kernel, atomicAdd into out.
// ---------------------------------------------------------------------------
#define P   8
#define FMC 1024
#define OUTER_PER_BLK (BLK * P)
__global__ __launch_bounds__(BLK) void chamfer_full_kernel(
    const float* __restrict__ x, const float* __restrict__ y,
    float* __restrict__ out)
{
    const int role = blockIdx.z;
    const int b    = blockIdx.y;
    const int oc   = blockIdx.x;
    const float* __restrict__ outer = (role == 0) ? x : y;
    const float* __restrict__ inner = (role == 0) ? y : x;
    const int tid = threadIdx.x;
    const int n0  = oc * OUTER_PER_BLK;

    __shared__ float4 lds[FMC];

    float nx0[P], nx1[P], nx2[P], xn[P], tmin[P];
#pragma unroll
    for (int p = 0; p < P; ++p) {
        const int n = n0 + p * BLK + tid;
        const float* xp = outer + ((size_t)b * S + n) * 3;
        const float a0 = xp[0], a1 = xp[1], a2 = xp[2];
        nx0[p] = -a0; nx1[p] = -a1; nx2[p] = -a2;
        xn[p]  = a0 * a0 + a1 * a1 + a2 * a2;
        tmin[p] = 3.0e38f;
    }

    for (int m0 = 0; m0 < S; m0 += FMC) {
        __syncthreads();
        for (int i = tid; i < FMC; i += BLK) {
            const float* yp = inner + ((size_t)b * S + m0 + i) * 3;
            const float a0 = yp[0], a1 = yp[1], a2 = yp[2];
            lds[i] = make_float4(a0, a1, a2,
                                 0.5f * (a0 * a0 + a1 * a1 + a2 * a2));
        }
        __syncthreads();
#pragma unroll 4
        for (int j = 0; j < FMC; ++j) {
            const float4 v = lds[j];
#pragma unroll
            for (int p = 0; p < P; ++p) {
                const float t = fmaf(nx0[p], v.x,
                                 fmaf(nx1[p], v.y,
                                  fmaf(nx2[p], v.z, v.w)));
                tmin[p] = fminf(tmin[p], t);
            }
        }
    }

    float s = 0.0f;
#pragma unroll
    for (int p = 0; p < P; ++p)
        s += sqrtf(fmaxf(fmaf(2.0f, tmin[p], xn[p]), 0.0f));

    __shared__ float red[BLK];
    red[tid] = s;
    __syncthreads();
    for (int off = BLK / 2; off > 0; off >>= 1) {
        if (tid < off) red[tid] += red[tid + off];
        __syncthreads();
    }
    if (tid == 0) atomicAdd(&out[b], red[0] * (0.5f / (float)S));
}

extern "C" void kernel_launch(void* const* d_in, const int* in_sizes, int n_in,
                              void* d_out, int out_size, void* d_ws, size_t ws_size,
                              hipStream_t stream) {
    const float* x = (const float*)d_in[0];
    const float* y = (const float*)d_in[1];
    float* out = (float*)d_out;

    // ws0: [YC_N][BATCH][S] floats, ws1: [XC_N][BATCH][S] floats
    const size_t n_ws0 = (size_t)YC_N * BATCH * S;
    const size_t n_ws1 = (size_t)XC_N * BATCH * S;
    const size_t need  = (n_ws0 + n_ws1) * sizeof(float);   // ~8.5 MB
    if (ws_size >= need) {
        float* ws0 = (float*)d_ws;
        float* ws1 = ws0 + n_ws0;
        chamfer_mfma_kernel<<<dim3(XC_N, BATCH, YC_N), BLK, 0, stream>>>(
            x, y, ws0, ws1);
        chamfer_reduce_kernel<<<BATCH, RBLK, 0, stream>>>(ws0, ws1, out);
    } else {
        hipMemsetAsync(d_out, 0, BATCH * sizeof(float), stream);
        chamfer_full_kernel<<<dim3(S / OUTER_PER_BLK, BATCH, 2), BLK, 0, stream>>>(
            x, y, out);
    }
}

// Round 5
// 40.720 us; speedup vs baseline: 2.1502x; 2.1502x over previous
//
#include <hip/hip_runtime.h>
#include <cstdint>
#include <cstddef>

#define S      4096
#define BATCH  16
#define BLK    256
#define YSPAN  2048                 // y range per block (z-dim splits S into 2)
#define CHUNK  512                  // y points staged per chunk
#define NTILE  (CHUNK / 32)         // 16 tiles of 32 y-points
#define NCHUNK (YSPAN / CHUNK)      // 4
#define ROWS_PER_BLOCK 128          // 4 waves x 32 rows
#define XC_N   (S / ROWS_PER_BLOCK) // 32 x-chunks
#define YC_N   (S / YSPAN)          // 2 y-slabs

typedef _Float16 half8   __attribute__((ext_vector_type(8)));
typedef float    floatx16 __attribute__((ext_vector_type(16)));

__device__ inline unsigned pack2(_Float16 lo, _Float16 hi) {
    unsigned short a = __builtin_bit_cast(unsigned short, lo);
    unsigned short b = __builtin_bit_cast(unsigned short, hi);
    return (unsigned)a | ((unsigned)b << 16);
}

// ---------------------------------------------------------------------------
// One MFMA per 32x32 tile computes D = d^2/2 for 1024 pairs:
//   A lanes 0-31  (k0-7):  [-xh0,-xh1,-xh2, -xh0,-xh1,-xh2, -xl0,-xl1]
//   A lanes 32-63 (k8-15): [-xl2, 1, 1, xnh, xnl, 0, 0, 0]
//   B lanes 0-31  (k0-7):  [yh0,yh1,yh2, yl0,yl1,yl2, yh0,yh1]
//   B lanes 32-63 (k8-15): [yh2, hh, hl, 1, 1, 0, 0, 0]
// where *h/*l = f16 hi/lo split, h = |y|^2/2, xn = |x|^2/2.
// D = xn + h - x.y = d^2/2 (error ~1e-6).  C/D: col=lane&31,
// row=(reg&3)+8*(reg>>2)+4*(lane>>5).
//
// No global atomics, no workspace init: block (xc,b,yc) writes its final
// row-mins (over its y-slab) to ws0[yc][b][128 rows], and its col-min
// partials (over its 128 rows) to ws1[xc][b][2048 cols] - every slot
// written exactly once. Also zeroes out[b] (one thread per b) so the
// reduce pass can atomicAdd without any hipMemsetAsync in the graph.
// ---------------------------------------------------------------------------
__global__ __launch_bounds__(BLK) void chamfer_mfma_kernel(
    const float* __restrict__ x, const float* __restrict__ y,
    float* __restrict__ ws0, float* __restrict__ ws1,
    float* __restrict__ out)
{
    const int b    = blockIdx.y;
    const int xc   = blockIdx.x;          // 0..31
    const int yc   = blockIdx.z;          // 0..1
    const int tid  = threadIdx.x;
    const int lane = tid & 63;
    const int wave = tid >> 6;            // 0..3
    const int hi32 = lane >> 5;
    const int l31  = lane & 31;

    if (xc == 0 && yc == 0 && tid == 0) out[b] = 0.0f;

    __shared__ uint4    ldsb[2][NTILE][64];
    __shared__ unsigned colmin[YSPAN];

    for (int i = tid; i < YSPAN; i += BLK) colmin[i] = 0x7F7F7F7Fu;
    // constant .z/.w of the upper-lane B slots: [e4=1, e5..7=0]
    for (int i = tid; i < 2 * NTILE * 32; i += BLK) {
        int bu = i / (NTILE * 32); int r = i % (NTILE * 32);
        ldsb[bu][r >> 5][32 + (r & 31)].z = 0x00003C00u;  // pack(1.0h, 0h)
        ldsb[bu][r >> 5][32 + (r & 31)].w = 0u;
    }

    // ---- A fragment (this wave's 32 x-rows; both lane-halves load same row)
    const int row = xc * ROWS_PER_BLOCK + wave * 32 + l31;
    const float* xp = x + ((size_t)b * S + row) * 3;
    const float x0 = xp[0], x1 = xp[1], x2 = xp[2];
    const float xn = 0.5f * (x0 * x0 + x1 * x1 + x2 * x2);
    const _Float16 xh0 = (_Float16)x0, xh1 = (_Float16)x1, xh2 = (_Float16)x2;
    const _Float16 xl0 = (_Float16)(x0 - (float)xh0);
    const _Float16 xl1 = (_Float16)(x1 - (float)xh1);
    const _Float16 xl2 = (_Float16)(x2 - (float)xh2);
    const _Float16 xnh = (_Float16)xn;
    const _Float16 xnl = (_Float16)(xn - (float)xnh);
    half8 afrag;
    if (hi32 == 0) {
        afrag[0] = -xh0; afrag[1] = -xh1; afrag[2] = -xh2;
        afrag[3] = -xh0; afrag[4] = -xh1; afrag[5] = -xh2;
        afrag[6] = -xl0; afrag[7] = -xl1;
    } else {
        afrag[0] = -xl2; afrag[1] = (_Float16)1.0f; afrag[2] = (_Float16)1.0f;
        afrag[3] = xnh;  afrag[4] = xnl;
        afrag[5] = (_Float16)0.0f; afrag[6] = (_Float16)0.0f; afrag[7] = (_Float16)0.0f;
    }

    floatx16 runrow;
#pragma unroll
    for (int r = 0; r < 16; ++r) runrow[r] = 3.0e38f;
    const floatx16 zeroacc = {};

    const int ybase = yc * YSPAN;
    const float* ysrc = y + ((size_t)b * S + ybase) * 3;

    auto stage = [&](int cc) {
        const int buf = cc & 1;
#pragma unroll
        for (int q = 0; q < 2; ++q) {
            const int pl = tid * 2 + q;            // 0..CHUNK
            const int p  = cc * CHUNK + pl;        // within YSPAN
            const float* yp = ysrc + (size_t)p * 3;
            const float y0 = yp[0], y1 = yp[1], y2 = yp[2];
            const float h  = 0.5f * (y0 * y0 + y1 * y1 + y2 * y2);
            const _Float16 a0 = (_Float16)y0, a1 = (_Float16)y1, a2 = (_Float16)y2;
            const _Float16 b0 = (_Float16)(y0 - (float)a0);
            const _Float16 b1 = (_Float16)(y1 - (float)a1);
            const _Float16 b2 = (_Float16)(y2 - (float)a2);
            const _Float16 hh = (_Float16)h;
            const _Float16 hl = (_Float16)(h - (float)hh);
            const int t = pl >> 5, col = pl & 31;
            ldsb[buf][t][col] = make_uint4(pack2(a0, a1), pack2(a2, b0),
                                           pack2(b1, b2), pack2(a0, a1));
            *(uint2*)&ldsb[buf][t][32 + col] =
                make_uint2(pack2(a2, hh), pack2(hl, (_Float16)1.0f));
        }
    };

    stage(0);
    __syncthreads();

    for (int c = 0; c < NCHUNK; ++c) {
        if (c + 1 < NCHUNK) stage(c + 1);
        const int buf = c & 1;
#pragma unroll 4
        for (int t = 0; t < NTILE; ++t) {
            const uint4 braw = ldsb[buf][t][lane];
            const half8 bfrag = __builtin_bit_cast(half8, braw);
            const floatx16 d =
                __builtin_amdgcn_mfma_f32_32x32x16_f16(afrag, bfrag, zeroacc, 0, 0, 0);
            // x-direction: running row mins (16 rows per lane)
#pragma unroll
            for (int r = 0; r < 16; ++r) runrow[r] = fminf(runrow[r], d[r]);
            // y-direction: fold 16 regs, then lane-halves
            float m = fminf(fminf(d[0], d[1]), d[2]);
            m = fminf(fminf(m, d[3]), d[4]);
            m = fminf(fminf(m, d[5]), d[6]);
            m = fminf(fminf(m, d[7]), d[8]);
            m = fminf(fminf(m, d[9]), d[10]);
            m = fminf(fminf(m, d[11]), d[12]);
            m = fminf(fminf(m, d[13]), d[14]);
            m = fminf(m, d[15]);
            m = fminf(m, __shfl_xor(m, 32));
            m = fmaxf(m, 0.0f);
            if (lane < 32)
                atomicMin(&colmin[c * CHUNK + t * 32 + l31], __float_as_uint(m));
        }
        __syncthreads();
    }

    // ---- x-direction flush: butterfly over the 32 cols, plain store rows
#pragma unroll
    for (int r = 0; r < 16; ++r) {
        float v = runrow[r];
        v = fminf(v, __shfl_xor(v, 1));
        v = fminf(v, __shfl_xor(v, 2));
        v = fminf(v, __shfl_xor(v, 4));
        v = fminf(v, __shfl_xor(v, 8));
        v = fminf(v, __shfl_xor(v, 16));
        runrow[r] = v;
    }
    if (l31 == 0) {
        float* w0 = ws0 + ((size_t)yc * BATCH + b) * S
                        + xc * ROWS_PER_BLOCK + wave * 32;
#pragma unroll
        for (int r = 0; r < 16; ++r) {
            const int rr = (r & 3) + 8 * (r >> 2) + 4 * hi32;
            w0[rr] = fmaxf(runrow[r], 0.0f);
        }
    }

    // ---- y-direction flush (loop-end barrier already synced all LDS mins)
    float* w1 = ws1 + ((size_t)xc * BATCH + b) * S + ybase;
    for (int i = tid; i < YSPAN; i += BLK)
        w1[i] = __uint_as_float(colmin[i]);
}

// ---------------------------------------------------------------------------
// Pass 2: grid (RSEG, BATCH). Each block owns 256 columns of batch b:
// fold ws0 over 2 y-slabs and ws1 over 32 x-chunks (coalesced: lane i
// reads col c0+i), sqrt-sum, one atomicAdd per block into out[b]
// (out was zeroed by pass 1; dispatch order guarantees visibility).
// ---------------------------------------------------------------------------
#define RSEG   (S / BLK)            // 16 segments of 256 cols
__global__ __launch_bounds__(BLK) void chamfer_reduce_kernel(
    const float* __restrict__ ws0, const float* __restrict__ ws1,
    float* __restrict__ out)
{
    const int b   = blockIdx.y;
    const int i   = blockIdx.x * BLK + threadIdx.x;   // column / row index
    const int tid = threadIdx.x;

    // x-direction rows: min over the 2 y-slabs
    const float mx = fminf(ws0[(size_t)b * S + i],
                           ws0[((size_t)BATCH + b) * S + i]);
    // y-direction cols: min over the 32 x-chunk partials
    float my = 3.0e38f;
#pragma unroll
    for (int xc = 0; xc < XC_N; ++xc)
        my = fminf(my, ws1[((size_t)xc * BATCH + b) * S + i]);

    float s = sqrtf(2.0f * mx) + sqrtf(2.0f * my);

    __shared__ float red[BLK];
    red[tid] = s;
    __syncthreads();
    for (int off = BLK / 2; off > 0; off >>= 1) {
        if (tid < off) red[tid] += red[tid + off];
        __syncthreads();
    }
    if (tid == 0) atomicAdd(&out[b], red[0] * (0.5f / (float)S));
}

// ---------------------------------------------------------------------------
// Fallback (no workspace): scalar full-range kernel, atomicAdd into out.
// ---------------------------------------------------------------------------
#define P   8
#define FMC 1024
#define OUTER_PER_BLK (BLK * P)
__global__ __launch_bounds__(BLK) void chamfer_full_kernel(
    const float* __restrict__ x, const float* __restrict__ y,
    float* __restrict__ out)
{
    const int role = blockIdx.z;
    const int b    = blockIdx.y;
    const int oc   = blockIdx.x;
    const float* __restrict__ outer = (role == 0) ? x : y;
    const float* __restrict__ inner = (role == 0) ? y : x;
    const int tid = threadIdx.x;
    const int n0  = oc * OUTER_PER_BLK;

    __shared__ float4 lds[FMC];

    float nx0[P], nx1[P], nx2[P], xn[P], tmin[P];
#pragma unroll
    for (int p = 0; p < P; ++p) {
        const int n = n0 + p * BLK + tid;
        const float* xp = outer + ((size_t)b * S + n) * 3;
        const float a0 = xp[0], a1 = xp[1], a2 = xp[2];
        nx0[p] = -a0; nx1[p] = -a1; nx2[p] = -a2;
        xn[p]  = a0 * a0 + a1 * a1 + a2 * a2;
        tmin[p] = 3.0e38f;
    }

    for (int m0 = 0; m0 < S; m0 += FMC) {
        __syncthreads();
        for (int i = tid; i < FMC; i += BLK) {
            const float* yp = inner + ((size_t)b * S + m0 + i) * 3;
            const float a0 = yp[0], a1 = yp[1], a2 = yp[2];
            lds[i] = make_float4(a0, a1, a2,
                                 0.5f * (a0 * a0 + a1 * a1 + a2 * a2));
        }
        __syncthreads();
#pragma unroll 4
        for (int j = 0; j < FMC; ++j) {
            const float4 v = lds[j];
#pragma unroll
            for (int p = 0; p < P; ++p) {
                const float t = fmaf(nx0[p], v.x,
                                 fmaf(nx1[p], v.y,
                                  fmaf(nx2[p], v.z, v.w)));
                tmin[p] = fminf(tmin[p], t);
            }
        }
    }

    float s = 0.0f;
#pragma unroll
    for (int p = 0; p < P; ++p)
        s += sqrtf(fmaxf(fmaf(2.0f, tmin[p], xn[p]), 0.0f));

    __shared__ float red[BLK];
    red[tid] = s;
    __syncthreads();
    for (int off = BLK / 2; off > 0; off >>= 1) {
        if (tid < off) red[tid] += red[tid + off];
        __syncthreads();
    }
    if (tid == 0) atomicAdd(&out[b], red[0] * (0.5f / (float)S));
}

extern "C" void kernel_launch(void* const* d_in, const int* in_sizes, int n_in,
                              void* d_out, int out_size, void* d_ws, size_t ws_size,
                              hipStream_t stream) {
    const float* x = (const float*)d_in[0];
    const float* y = (const float*)d_in[1];
    float* out = (float*)d_out;

    // ws0: [YC_N][BATCH][S] floats, ws1: [XC_N][BATCH][S] floats
    const size_t n_ws0 = (size_t)YC_N * BATCH * S;
    const size_t n_ws1 = (size_t)XC_N * BATCH * S;
    const size_t need  = (n_ws0 + n_ws1) * sizeof(float);   // ~8.5 MB
    if (ws_size >= need) {
        float* ws0 = (float*)d_ws;
        float* ws1 = ws0 + n_ws0;
        chamfer_mfma_kernel<<<dim3(XC_N, BATCH, YC_N), BLK, 0, stream>>>(
            x, y, ws0, ws1, out);
        chamfer_reduce_kernel<<<dim3(RSEG, BATCH), BLK, 0, stream>>>(
            ws0, ws1, out);
    } else {
        hipMemsetAsync(d_out, 0, BATCH * sizeof(float), stream);
        chamfer_full_kernel<<<dim3(S / OUTER_PER_BLK, BATCH, 2), BLK, 0, stream>>>(
            x, y, out);
    }
}

// Round 6
// 35.885 us; speedup vs baseline: 2.4400x; 1.1347x over previous
//
#include <hip/hip_runtime.h>
#include <cstdint>
#include <cstddef>

#define S      4096
#define BATCH  16
#define BLK    256
#define YSPAN  1024                 // y range per block (z-dim splits S into 4)
#define CHUNK  256                  // y points staged per chunk (1/thread)
#define NTILE  (CHUNK / 32)         // 8 tiles of 32 y-points
#define NCHUNK (YSPAN / CHUNK)      // 4
#define ROWS_PER_BLOCK 128          // 4 waves x 32 rows
#define XC_N   (S / ROWS_PER_BLOCK) // 32 x-chunks
#define YC_N   (S / YSPAN)          // 4 y-slabs

typedef _Float16 half8   __attribute__((ext_vector_type(8)));
typedef float    floatx16 __attribute__((ext_vector_type(16)));

__device__ inline unsigned pack2(_Float16 lo, _Float16 hi) {
    unsigned short a = __builtin_bit_cast(unsigned short, lo);
    unsigned short b = __builtin_bit_cast(unsigned short, hi);
    return (unsigned)a | ((unsigned)b << 16);
}

// ---------------------------------------------------------------------------
// One MFMA per 32x32 tile computes D = d^2/2 for 1024 pairs:
//   A lanes 0-31  (k0-7):  [-xh0,-xh1,-xh2, -xh0,-xh1,-xh2, -xl0,-xl1]
//   A lanes 32-63 (k8-15): [-xl2, 1, 1, xnh, xnl, 0, 0, 0]
//   B lanes 0-31  (k0-7):  [yh0,yh1,yh2, yl0,yl1,yl2, yh0,yh1]
//   B lanes 32-63 (k8-15): [yh2, hh, hl, 1, 1, 0, 0, 0]
// where *h/*l = f16 hi/lo split, h = |y|^2/2, xn = |x|^2/2.
// D = xn + h - x.y = d^2/2 (error ~1e-6).  C/D: col=lane&31,
// row=(reg&3)+8*(reg>>2)+4*(lane>>5).
//
// R6 changes vs R5: no __shfl_xor(m,32) (its ds_bpermute lgkmcnt-wait
// drained the prefetched ds_reads every tile) -- lanes l and l+32 both
// atomicMin colmin directly (fire-and-forget ds_min). min3-shaped fold.
// YSPAN 1024 / CHUNK 256 -> 20KB LDS, 2048 blocks -> higher occupancy.
// ---------------------------------------------------------------------------
__global__ __launch_bounds__(BLK, 5) void chamfer_mfma_kernel(
    const float* __restrict__ x, const float* __restrict__ y,
    float* __restrict__ ws0, float* __restrict__ ws1,
    float* __restrict__ out)
{
    const int b    = blockIdx.y;
    const int xc   = blockIdx.x;          // 0..31
    const int yc   = blockIdx.z;          // 0..3
    const int tid  = threadIdx.x;
    const int lane = tid & 63;
    const int wave = tid >> 6;            // 0..3
    const int hi32 = lane >> 5;
    const int l31  = lane & 31;

    if (xc == 0 && yc == 0 && tid == 0) out[b] = 0.0f;

    __shared__ uint4    ldsb[2][NTILE][64];
    __shared__ unsigned colmin[YSPAN];

    for (int i = tid; i < YSPAN; i += BLK) colmin[i] = 0x7F7F7F7Fu;
    // constant .z/.w of the upper-lane B slots: [e4=1, e5..7=0];
    // stage() only overwrites .x/.y of these entries.
    for (int i = tid; i < 2 * NTILE * 32; i += BLK) {
        int bu = i / (NTILE * 32); int r = i % (NTILE * 32);
        ldsb[bu][r >> 5][32 + (r & 31)].z = 0x00003C00u;  // pack(1.0h, 0h)
        ldsb[bu][r >> 5][32 + (r & 31)].w = 0u;
    }

    // ---- A fragment (this wave's 32 x-rows; both lane-halves load same row)
    const int row = xc * ROWS_PER_BLOCK + wave * 32 + l31;
    const float* xp = x + ((size_t)b * S + row) * 3;
    const float x0 = xp[0], x1 = xp[1], x2 = xp[2];
    const float xn = 0.5f * (x0 * x0 + x1 * x1 + x2 * x2);
    const _Float16 xh0 = (_Float16)x0, xh1 = (_Float16)x1, xh2 = (_Float16)x2;
    const _Float16 xl0 = (_Float16)(x0 - (float)xh0);
    const _Float16 xl1 = (_Float16)(x1 - (float)xh1);
    const _Float16 xl2 = (_Float16)(x2 - (float)xh2);
    const _Float16 xnh = (_Float16)xn;
    const _Float16 xnl = (_Float16)(xn - (float)xnh);
    half8 afrag;
    if (hi32 == 0) {
        afrag[0] = -xh0; afrag[1] = -xh1; afrag[2] = -xh2;
        afrag[3] = -xh0; afrag[4] = -xh1; afrag[5] = -xh2;
        afrag[6] = -xl0; afrag[7] = -xl1;
    } else {
        afrag[0] = -xl2; afrag[1] = (_Float16)1.0f; afrag[2] = (_Float16)1.0f;
        afrag[3] = xnh;  afrag[4] = xnl;
        afrag[5] = (_Float16)0.0f; afrag[6] = (_Float16)0.0f; afrag[7] = (_Float16)0.0f;
    }

    floatx16 runrow;
#pragma unroll
    for (int r = 0; r < 16; ++r) runrow[r] = 3.0e38f;
    const floatx16 zeroacc = {};

    const int ybase = yc * YSPAN;
    const float* ysrc = y + ((size_t)b * S + ybase) * 3;

    auto stage = [&](int cc) {
        const int buf = cc & 1;
        const int p   = cc * CHUNK + tid;          // within YSPAN
        const float* yp = ysrc + (size_t)p * 3;
        const float y0 = yp[0], y1 = yp[1], y2 = yp[2];
        const float h  = 0.5f * (y0 * y0 + y1 * y1 + y2 * y2);
        const _Float16 a0 = (_Float16)y0, a1 = (_Float16)y1, a2 = (_Float16)y2;
        const _Float16 b0 = (_Float16)(y0 - (float)a0);
        const _Float16 b1 = (_Float16)(y1 - (float)a1);
        const _Float16 b2 = (_Float16)(y2 - (float)a2);
        const _Float16 hh = (_Float16)h;
        const _Float16 hl = (_Float16)(h - (float)hh);
        const int t = tid >> 5, col = tid & 31;
        ldsb[buf][t][col] = make_uint4(pack2(a0, a1), pack2(a2, b0),
                                       pack2(b1, b2), pack2(a0, a1));
        *(uint2*)&ldsb[buf][t][32 + col] =
            make_uint2(pack2(a2, hh), pack2(hl, (_Float16)1.0f));
    };

    stage(0);
    __syncthreads();

    for (int c = 0; c < NCHUNK; ++c) {
        if (c + 1 < NCHUNK) stage(c + 1);
        const int buf = c & 1;
#pragma unroll
        for (int t = 0; t < NTILE; ++t) {
            const uint4 braw = ldsb[buf][t][lane];
            const half8 bfrag = __builtin_bit_cast(half8, braw);
            const floatx16 d =
                __builtin_amdgcn_mfma_f32_32x32x16_f16(afrag, bfrag, zeroacc, 0, 0, 0);
            // x-direction: running row mins (16 rows per lane)
#pragma unroll
            for (int r = 0; r < 16; ++r) runrow[r] = fminf(runrow[r], d[r]);
            // y-direction: min3-shaped fold of the 16 regs (per-lane = this
            // lane-half's 16 rows of col l31), then 64-lane LDS atomicMin
            // (lanes l and l+32 share an address -> 2-way DS serialize, no
            // cross-lane shuffle, no lgkmcnt drain).
            const float m1 = fminf(fminf(d[0],  d[1]),  d[2]);
            const float m2 = fminf(fminf(d[3],  d[4]),  d[5]);
            const float m3 = fminf(fminf(d[6],  d[7]),  d[8]);
            const float m4 = fminf(fminf(d[9],  d[10]), d[11]);
            const float m5 = fminf(fminf(d[12], d[13]), d[14]);
            float m = fminf(fminf(m1, m2), m3);
            m = fminf(fminf(m, m4), m5);
            m = fminf(m, d[15]);
            m = fmaxf(m, 0.0f);
            atomicMin(&colmin[c * CHUNK + t * 32 + l31], __float_as_uint(m));
        }
        __syncthreads();
    }

    // ---- x-direction flush: butterfly over the 32 cols, plain store rows
#pragma unroll
    for (int r = 0; r < 16; ++r) {
        float v = runrow[r];
        v = fminf(v, __shfl_xor(v, 1));
        v = fminf(v, __shfl_xor(v, 2));
        v = fminf(v, __shfl_xor(v, 4));
        v = fminf(v, __shfl_xor(v, 8));
        v = fminf(v, __shfl_xor(v, 16));
        runrow[r] = v;
    }
    if (l31 == 0) {
        float* w0 = ws0 + ((size_t)yc * BATCH + b) * S
                        + xc * ROWS_PER_BLOCK + wave * 32;
#pragma unroll
        for (int r = 0; r < 16; ++r) {
            const int rr = (r & 3) + 8 * (r >> 2) + 4 * hi32;
            w0[rr] = fmaxf(runrow[r], 0.0f);
        }
    }

    // ---- y-direction flush (loop-end barrier already synced all LDS mins)
    float* w1 = ws1 + ((size_t)xc * BATCH + b) * S + ybase;
    for (int i = tid; i < YSPAN; i += BLK)
        w1[i] = __uint_as_float(colmin[i]);
}

// ---------------------------------------------------------------------------
// Pass 2: grid (RSEG, BATCH). Each block owns 256 columns of batch b:
// fold ws0 over 4 y-slabs and ws1 over 32 x-chunks (coalesced), sqrt-sum,
// one atomicAdd per block into out[b] (out zeroed by pass 1).
// ---------------------------------------------------------------------------
#define RSEG   (S / BLK)            // 16 segments of 256 cols
__global__ __launch_bounds__(BLK) void chamfer_reduce_kernel(
    const float* __restrict__ ws0, const float* __restrict__ ws1,
    float* __restrict__ out)
{
    const int b   = blockIdx.y;
    const int i   = blockIdx.x * BLK + threadIdx.x;   // column / row index
    const int tid = threadIdx.x;

    // x-direction rows: min over the 4 y-slabs
    float mx = 3.0e38f;
#pragma unroll
    for (int yc = 0; yc < YC_N; ++yc)
        mx = fminf(mx, ws0[((size_t)yc * BATCH + b) * S + i]);
    // y-direction cols: min over the 32 x-chunk partials
    float my = 3.0e38f;
#pragma unroll
    for (int xc = 0; xc < XC_N; ++xc)
        my = fminf(my, ws1[((size_t)xc * BATCH + b) * S + i]);

    float s = sqrtf(2.0f * mx) + sqrtf(2.0f * my);

    __shared__ float red[BLK];
    red[tid] = s;
    __syncthreads();
    for (int off = BLK / 2; off > 0; off >>= 1) {
        if (tid < off) red[tid] += red[tid + off];
        __syncthreads();
    }
    if (tid == 0) atomicAdd(&out[b], red[0] * (0.5f / (float)S));
}

// ---------------------------------------------------------------------------
// Fallback (no workspace): scalar full-range kernel, atomicAdd into out.
// ---------------------------------------------------------------------------
#define P   8
#define FMC 1024
#define OUTER_PER_BLK (BLK * P)
__global__ __launch_bounds__(BLK) void chamfer_full_kernel(
    const float* __restrict__ x, const float* __restrict__ y,
    float* __restrict__ out)
{
    const int role = blockIdx.z;
    const int b    = blockIdx.y;
    const int oc   = blockIdx.x;
    const float* __restrict__ outer = (role == 0) ? x : y;
    const float* __restrict__ inner = (role == 0) ? y : x;
    const int tid = threadIdx.x;
    const int n0  = oc * OUTER_PER_BLK;

    __shared__ float4 lds[FMC];

    float nx0[P], nx1[P], nx2[P], xn[P], tmin[P];
#pragma unroll
    for (int p = 0; p < P; ++p) {
        const int n = n0 + p * BLK + tid;
        const float* xp = outer + ((size_t)b * S + n) * 3;
        const float a0 = xp[0], a1 = xp[1], a2 = xp[2];
        nx0[p] = -a0; nx1[p] = -a1; nx2[p] = -a2;
        xn[p]  = a0 * a0 + a1 * a1 + a2 * a2;
        tmin[p] = 3.0e38f;
    }

    for (int m0 = 0; m0 < S; m0 += FMC) {
        __syncthreads();
        for (int i = tid; i < FMC; i += BLK) {
            const float* yp = inner + ((size_t)b * S + m0 + i) * 3;
            const float a0 = yp[0], a1 = yp[1], a2 = yp[2];
            lds[i] = make_float4(a0, a1, a2,
                                 0.5f * (a0 * a0 + a1 * a1 + a2 * a2));
        }
        __syncthreads();
#pragma unroll 4
        for (int j = 0; j < FMC; ++j) {
            const float4 v = lds[j];
#pragma unroll
            for (int p = 0; p < P; ++p) {
                const float t = fmaf(nx0[p], v.x,
                                 fmaf(nx1[p], v.y,
                                  fmaf(nx2[p], v.z, v.w)));
                tmin[p] = fminf(tmin[p], t);
            }
        }
    }

    float s = 0.0f;
#pragma unroll
    for (int p = 0; p < P; ++p)
        s += sqrtf(fmaxf(fmaf(2.0f, tmin[p], xn[p]), 0.0f));

    __shared__ float red[BLK];
    red[tid] = s;
    __syncthreads();
    for (int off = BLK / 2; off > 0; off >>= 1) {
        if (tid < off) red[tid] += red[tid + off];
        __syncthreads();
    }
    if (tid == 0) atomicAdd(&out[b], red[0] * (0.5f / (float)S));
}

extern "C" void kernel_launch(void* const* d_in, const int* in_sizes, int n_in,
                              void* d_out, int out_size, void* d_ws, size_t ws_size,
                              hipStream_t stream) {
    const float* x = (const float*)d_in[0];
    const float* y = (const float*)d_in[1];
    float* out = (float*)d_out;

    // ws0: [YC_N][BATCH][S] floats, ws1: [XC_N][BATCH][S] floats
    const size_t n_ws0 = (size_t)YC_N * BATCH * S;
    const size_t n_ws1 = (size_t)XC_N * BATCH * S;
    const size_t need  = (n_ws0 + n_ws1) * sizeof(float);   // ~9 MB
    if (ws_size >= need) {
        float* ws0 = (float*)d_ws;
        float* ws1 = ws0 + n_ws0;
        chamfer_mfma_kernel<<<dim3(XC_N, BATCH, YC_N), BLK, 0, stream>>>(
            x, y, ws0, ws1, out);
        chamfer_reduce_kernel<<<dim3(RSEG, BATCH), BLK, 0, stream>>>(
            ws0, ws1, out);
    } else {
        hipMemsetAsync(d_out, 0, BATCH * sizeof(float), stream);
        chamfer_full_kernel<<<dim3(S / OUTER_PER_BLK, BATCH, 2), BLK, 0, stream>>>(
            x, y, out);
    }
}